// Round 2
// baseline (502.006 us; speedup 1.0000x reference)
//
#include <hip/hip_runtime.h>
#include <stdint.h>

// Problem constants: B=8, H=W=64, C=256
#define NB    8
#define NTOK  4096          // H*W tokens per batch
#define TOK   32768         // NB*NTOK
#define CDIM  256
#define BQ    128           // queries per block (flash): 32 per wave-pair
#define BK    64            // keys per LDS tile (flash); split 32/32 across wave halves
#define NT    (NTOK / BK)   // 64 key tiles

// Unpadded, XOR-swizzled tiles: conflict avoidance comes from the swizzle
// (byte ^= (row&7)<<4, baked into the GLOBAL layout by qkv, re-applied at the
// flash read; DMA copies linearly so the swizzle survives — both-sides rule).
#define KTILE_SH (BK * CDIM)     // 16384 shorts = 32768 B  (32 x 1KB chunks)
#define VTILE_SH (CDIM * BK)     // 16384 shorts = 32768 B  (32 x 1KB chunks)
#define PLP   72                 // P LDS pitch in shorts (144 B, 16B-aligned rows)

typedef __attribute__((ext_vector_type(8))) short bf16x8;   // 8 bf16 = 4 VGPRs
typedef __attribute__((ext_vector_type(4))) float f32x4;    // MFMA C/D frag

#define SSCALE 0.09016844f   // C^-0.5 * log2(e) = 0.0625 * 1.442695

static __device__ __forceinline__ unsigned short f2bf(float f) {
    union { float f; unsigned u; } v; v.f = f;
    unsigned r = v.u + 0x7fffu + ((v.u >> 16) & 1u);   // RNE
    return (unsigned short)(r >> 16);
}

// async global->LDS DMA: 16 B/lane, LDS dest = uniform base + lane*16
static __device__ __forceinline__ void dma16(const unsigned short* g, unsigned short* l) {
    __builtin_amdgcn_global_load_lds(
        (const __attribute__((address_space(1))) unsigned int*)g,
        (__attribute__((address_space(3))) unsigned int*)l,
        16, 0, 0);
}

// ---------------- prep: LayerNorm (blocks 0..8191) + weight transpose -------
__global__ __launch_bounds__(256) void prep_kernel(
        const float* __restrict__ x,
        const float* __restrict__ gamma,
        const float* __restrict__ beta,
        const float* __restrict__ w0, const float* __restrict__ w1,
        const float* __restrict__ w2, const float* __restrict__ w3,
        unsigned short* __restrict__ h_bf,
        unsigned short* __restrict__ wt) {
    int bx = blockIdx.x;
    if (bx >= TOK / 4) {
        // weight transpose + bf16 cast: Wt[d][c] = W[c][d]
        int id = bx - TOK / 4;            // 0..1023
        int m = id >> 8, dd = id & 255;
        const float* src = (m == 0) ? w0 : (m == 1) ? w1 : (m == 2) ? w2 : w3;
        wt[m * (CDIM * CDIM) + dd * CDIM + threadIdx.x] = f2bf(src[threadIdx.x * CDIM + dd]);
        return;
    }
    int w = threadIdx.x >> 6;
    int lane = threadIdx.x & 63;
    int token = bx * 4 + w;
    const float4 xv = ((const float4*)(x + (size_t)token * CDIM))[lane];
    float s = xv.x + xv.y + xv.z + xv.w;
    #pragma unroll
    for (int off = 1; off < 64; off <<= 1) s += __shfl_xor(s, off, 64);
    float mean = s * (1.0f / 256.0f);
    float d0 = xv.x - mean, d1 = xv.y - mean, d2 = xv.z - mean, d3 = xv.w - mean;
    float ss = d0 * d0 + d1 * d1 + d2 * d2 + d3 * d3;
    #pragma unroll
    for (int off = 1; off < 64; off <<= 1) ss += __shfl_xor(ss, off, 64);
    float rstd = rsqrtf(ss * (1.0f / 256.0f) + 1e-5f);
    float4 g = ((const float4*)gamma)[lane];
    float4 b = ((const float4*)beta)[lane];
    ushort4 o;
    o.x = f2bf(d0 * rstd * g.x + b.x);
    o.y = f2bf(d1 * rstd * g.y + b.y);
    o.z = f2bf(d2 * rstd * g.z + b.z);
    o.w = f2bf(d3 * rstd * g.w + b.w);
    ((ushort4*)(h_bf + (size_t)token * CDIM))[lane] = o;
}

// ---------------- fused Q+K+V projection, 4-way column-split ----------------
// grid (512, 4), 128 thr. Block (bx,gy) = key tile bx, output columns
// nt = gy*4 .. gy*4+3 of ALL THREE projections. K/Vt written PRE-SWIZZLED
// (byte ^= (row&7)<<4 within each tile row) so the flash DMA can stay linear.
__global__ __launch_bounds__(128) void qkv_kernel(
        const unsigned short* __restrict__ h_bf,
        const unsigned short* __restrict__ wts,
        const float* __restrict__ bq,
        const float* __restrict__ bk,
        const float* __restrict__ bv,
        unsigned short* __restrict__ q_bf,
        unsigned short* __restrict__ k2,
        unsigned short* __restrict__ vt2) {
    __shared__ unsigned short VT[64][PLP];   // 9216 B (quarter tile: d in [gy*64, gy*64+64))
    int tid = threadIdx.x;
    int w = tid >> 6, lane = tid & 63, quad = lane >> 4, l16 = lane & 15;
    int blk = blockIdx.x;
    int gy = blockIdx.y;
    int nt0 = gy * 4;
    int tok_base = blk * 64 + w * 32;

    bf16x8 afr[2][8];
    #pragma unroll
    for (int s = 0; s < 2; ++s)
        #pragma unroll
        for (int kk = 0; kk < 8; ++kk)
            afr[s][kk] = *(const bf16x8*)(h_bf + (size_t)(tok_base + s * 16 + l16) * CDIM + kk * 32 + quad * 8);

    // ---- Q (pre-scaled by SSCALE)
    {
        const unsigned short* wq_t = wts;
        #pragma unroll
        for (int ntl = 0; ntl < 4; ++ntl) {
            int nt = nt0 + ntl;
            f32x4 acc0 = {0.f, 0.f, 0.f, 0.f};
            f32x4 acc1 = {0.f, 0.f, 0.f, 0.f};
            #pragma unroll
            for (int kk = 0; kk < 8; ++kk) {
                bf16x8 bfr = *(const bf16x8*)(wq_t + (size_t)(nt * 16 + l16) * CDIM + kk * 32 + quad * 8);
                acc0 = __builtin_amdgcn_mfma_f32_16x16x32_bf16(afr[0][kk], bfr, acc0, 0, 0, 0);
                acc1 = __builtin_amdgcn_mfma_f32_16x16x32_bf16(afr[1][kk], bfr, acc1, 0, 0, 0);
            }
            int d = nt * 16 + l16;
            float bb = bq[d];
            #pragma unroll
            for (int r = 0; r < 4; ++r) {
                q_bf[(size_t)(tok_base + quad * 4 + r) * CDIM + d]      = f2bf((acc0[r] + bb) * SSCALE);
                q_bf[(size_t)(tok_base + 16 + quad * 4 + r) * CDIM + d] = f2bf((acc1[r] + bb) * SSCALE);
            }
        }
    }
    // ---- K (into swizzled 64-key tile: short off = key*256 + (d ^ ((key&7)<<3)))
    {
        const unsigned short* wk_t = wts + CDIM * CDIM;
        unsigned short* kdst = k2 + (size_t)blk * KTILE_SH;
        int row0 = w * 32 + quad * 4;
        #pragma unroll
        for (int ntl = 0; ntl < 4; ++ntl) {
            int nt = nt0 + ntl;
            f32x4 acc0 = {0.f, 0.f, 0.f, 0.f};
            f32x4 acc1 = {0.f, 0.f, 0.f, 0.f};
            #pragma unroll
            for (int kk = 0; kk < 8; ++kk) {
                bf16x8 bfr = *(const bf16x8*)(wk_t + (size_t)(nt * 16 + l16) * CDIM + kk * 32 + quad * 8);
                acc0 = __builtin_amdgcn_mfma_f32_16x16x32_bf16(afr[0][kk], bfr, acc0, 0, 0, 0);
                acc1 = __builtin_amdgcn_mfma_f32_16x16x32_bf16(afr[1][kk], bfr, acc1, 0, 0, 0);
            }
            int d = nt * 16 + l16;
            float bb = bk[d];
            #pragma unroll
            for (int r = 0; r < 4; ++r) {
                int k0 = row0 + r;                       // (k0+16)&7 == k0&7
                int ds = d ^ ((k0 & 7) << 3);
                kdst[(size_t)k0 * 256 + ds]        = f2bf(acc0[r] + bb);
                kdst[(size_t)(k0 + 16) * 256 + ds] = f2bf(acc1[r] + bb);
            }
        }
    }
    // ---- V (transpose through quarter-height LDS into swizzled tile)
    {
        const unsigned short* wv_t = wts + 2 * CDIM * CDIM;
        int col0 = w * 32 + quad * 4;
        #pragma unroll
        for (int ntl = 0; ntl < 4; ++ntl) {
            int nt = nt0 + ntl;
            f32x4 acc0 = {0.f, 0.f, 0.f, 0.f};
            f32x4 acc1 = {0.f, 0.f, 0.f, 0.f};
            #pragma unroll
            for (int kk = 0; kk < 8; ++kk) {
                bf16x8 bfr = *(const bf16x8*)(wv_t + (size_t)(nt * 16 + l16) * CDIM + kk * 32 + quad * 8);
                acc0 = __builtin_amdgcn_mfma_f32_16x16x32_bf16(afr[0][kk], bfr, acc0, 0, 0, 0);
                acc1 = __builtin_amdgcn_mfma_f32_16x16x32_bf16(afr[1][kk], bfr, acc1, 0, 0, 0);
            }
            int d = nt * 16 + l16;
            float bb = bv[d];
            int dl = ntl * 16 + l16;          // local row (d - gy*64)
            #pragma unroll
            for (int r = 0; r < 4; ++r) {
                VT[dl][col0 + r]      = f2bf(acc0[r] + bb);
                VT[dl][col0 + 16 + r] = f2bf(acc1[r] + bb);
            }
        }
    }
    __syncthreads();
    // swizzled copy-out: 64 d-rows x 8 16B-chunks; chunk off ^= ((d&7)<<3) shorts
    #pragma unroll
    for (int j = 0; j < 4; ++j) {
        int idx = j * 128 + tid;          // 0..511
        int rr = idx >> 3;                // local d row 0..63
        int c8 = idx & 7;                 // 16B chunk (8 keys)
        const uint4* src = (const uint4*)(&VT[rr][c8 * 8]);
        int dsh = (gy * 64 + rr) * 64 + ((c8 * 8) ^ ((rr & 7) << 3));
        *(uint4*)(vt2 + (size_t)blk * VTILE_SH + dsh) = *src;
    }
}

// ---------------- Flash attention: key-split wave pairs, counted-vmcnt pipe --
// Round-0 body geometry (8 waves, 512 thr, BQ=128, wave w: q-rows (w&3)*32,
// key half (w>>2)), with two changes:
//  1. counted vmcnt: every wave issues exactly 8 DMA chunks per tile; the
//     barrier waits s_waitcnt vmcnt(8) (next tile stays in flight) instead of
//     __syncthreads' vmcnt(0) drain -> DMA delivery overlaps a full phase.
//  2. XOR-swizzled K/V LDS (pre-swizzled global, linear DMA, swizzled read):
//     kills the 16-way ds_read_b128 bank conflicts (8.4M conflict cycles).
#define DMA_TILE(KS, VS, ktn)                                                        \
    {                                                                                \
        const unsigned short* gk = k2 + (size_t)(b * NT + (ktn)) * KTILE_SH;         \
        const unsigned short* gv = vt2 + (size_t)(b * NT + (ktn)) * VTILE_SH;        \
        _Pragma("unroll")                                                            \
        for (int i = 0; i < 8; ++i) {                                                \
            int c = w * 8 + i;                                                       \
            if (c < 32) dma16(gk + c * 512 + lane * 8, &KS[0][0] + c * 512);         \
            else dma16(gv + (c - 32) * 512 + lane * 8, &VS[0][0] + (c - 32) * 512);  \
        }                                                                            \
    }

#define WAITV(N)                                             \
    asm volatile("s_waitcnt vmcnt(" #N ")" ::: "memory");    \
    __builtin_amdgcn_sched_barrier(0);                       \
    __builtin_amdgcn_s_barrier();                            \
    __builtin_amdgcn_sched_barrier(0);

#define BARRIER()                                            \
    __builtin_amdgcn_sched_barrier(0);                       \
    __builtin_amdgcn_s_barrier();                            \
    __builtin_amdgcn_sched_barrier(0);

#define COMPUTE_TILE(KS, VS)                                                         \
    {                                                                                \
        f32x4 sfr[2][2];                                                             \
        __builtin_amdgcn_s_setprio(1);                                               \
        _Pragma("unroll")                                                            \
        for (int nt = 0; nt < 2; ++nt) {                                             \
            f32x4 a0 = {0.f, 0.f, 0.f, 0.f};                                         \
            f32x4 a1 = {0.f, 0.f, 0.f, 0.f};                                         \
            _Pragma("unroll")                                                        \
            for (int kk = 0; kk < 8; ++kk) {                                         \
                bf16x8 kb = *(const bf16x8*)(&KS[0][0]                               \
                    + (size_t)(kh * 32 + nt * 16 + l16) * 256                        \
                    + ((kk * 32 + quad * 8) ^ swz));                                 \
                a0 = __builtin_amdgcn_mfma_f32_16x16x32_bf16(qfr[0][kk], kb, a0, 0, 0, 0);      \
                a1 = __builtin_amdgcn_mfma_f32_16x16x32_bf16(qfr[1][kk], kb, a1, 0, 0, 0);      \
            }                                                                        \
            sfr[0][nt] = a0; sfr[1][nt] = a1;                                        \
        }                                                                            \
        __builtin_amdgcn_s_setprio(0);                                               \
        _Pragma("unroll")                                                            \
        for (int s = 0; s < 2; ++s)                                                  \
            _Pragma("unroll")                                                        \
            for (int nt = 0; nt < 2; ++nt)                                           \
                _Pragma("unroll")                                                    \
                for (int r = 0; r < 4; ++r) {                                        \
                    float p = __builtin_amdgcn_exp2f(sfr[s][nt][r]);                 \
                    lacc[s][r] += p;                                                 \
                    Pl[wq * 32 + s * 16 + quad * 4 + r][kh * 32 + nt * 16 + l16] =   \
                        (unsigned short)(__float_as_uint(p) >> 16);                  \
                }                                                                    \
        bf16x8 pfr0 = *(const bf16x8*)(&Pl[wq * 32 + l16][kh * 32 + quad * 8]);      \
        bf16x8 pfr1 = *(const bf16x8*)(&Pl[wq * 32 + 16 + l16][kh * 32 + quad * 8]); \
        __builtin_amdgcn_s_setprio(1);                                               \
        _Pragma("unroll")                                                            \
        for (int nt2 = 0; nt2 < 16; ++nt2) {                                         \
            bf16x8 vb = *(const bf16x8*)(&VS[0][0]                                   \
                + (size_t)(nt2 * 16 + l16) * 64                                      \
                + ((kh * 32 + quad * 8) ^ swz));                                     \
            O[0][nt2] = __builtin_amdgcn_mfma_f32_16x16x32_bf16(pfr0, vb, O[0][nt2], 0, 0, 0);  \
            O[1][nt2] = __builtin_amdgcn_mfma_f32_16x16x32_bf16(pfr1, vb, O[1][nt2], 0, 0, 0);  \
        }                                                                            \
        __builtin_amdgcn_s_setprio(0);                                               \
    }

__global__ __launch_bounds__(512, 2) void flash_kernel(
        const unsigned short* __restrict__ q_bf,
        const unsigned short* __restrict__ k2,
        const unsigned short* __restrict__ vt2,
        unsigned short* __restrict__ attn) {
    __shared__ unsigned short Ks0[BK][256];     // 32768 B
    __shared__ unsigned short Ks1[BK][256];     // 32768 B
    __shared__ unsigned short Vs0[CDIM][64];    // 32768 B
    __shared__ unsigned short Vs1[CDIM][64];    // 32768 B
    __shared__ unsigned short Pl[BQ][PLP];      // 18432 B  (total 149504 B)

    int tid = threadIdx.x;
    int w = tid >> 6, lane = tid & 63, quad = lane >> 4, l16 = lane & 15;
    int kh = w >> 2;        // key half of each tile
    int wq = w & 3;         // q-row group (shared with wave w^4)
    int swz = (l16 & 7) << 3;   // XOR swizzle term (shorts) — row&7 == l16&7
    int bid = blockIdx.x;
    int b = bid & 7;        // XCD swizzle: same batch -> same XCD L2
    int qtile = bid >> 3;
    int qrow = qtile * BQ + wq * 32;
    const size_t bbase = (size_t)b * NTOK * CDIM;

    bf16x8 qfr[2][8];
    #pragma unroll
    for (int s = 0; s < 2; ++s)
        #pragma unroll
        for (int kk = 0; kk < 8; ++kk)
            qfr[s][kk] = *(const bf16x8*)(q_bf + bbase + (size_t)(qrow + s * 16 + l16) * CDIM + kk * 32 + quad * 8);

    f32x4 O[2][16];
    #pragma unroll
    for (int s = 0; s < 2; ++s)
        #pragma unroll
        for (int i = 0; i < 16; ++i) O[s][i] = (f32x4){0.f, 0.f, 0.f, 0.f};
    float lacc[2][4] = {{0.f, 0.f, 0.f, 0.f}, {0.f, 0.f, 0.f, 0.f}};

    DMA_TILE(Ks0, Vs0, 0);

    for (int kt2 = 0; kt2 < NT; kt2 += 2) {
        DMA_TILE(Ks1, Vs1, kt2 + 1);
        WAITV(8)                              // tile kt2 arrived (all waves)
        COMPUTE_TILE(Ks0, Vs0);
        BARRIER()                             // everyone done reading Ks0/Vs0
        if (kt2 + 2 < NT) {
            DMA_TILE(Ks0, Vs0, kt2 + 2);
            WAITV(8)                          // tile kt2+1 arrived
        } else {
            WAITV(0)                          // last tile: full drain
        }
        COMPUTE_TILE(Ks1, Vs1);
        BARRIER()                             // everyone done reading Ks1/Vs1
    }

    // ---- epilogue: combine wave pairs (key halves) through dead LDS buffers
    float* sO = (wq == 0) ? (float*)&Ks0[0][0] : (wq == 1) ? (float*)&Ks1[0][0]
              : (wq == 2) ? (float*)&Vs0[0][0] : (float*)&Vs1[0][0];
    float* sL = (float*)&Pl[0][0] + wq * 512;    // 2*4*64 floats per pair

    if (kh == 1) {
        #pragma unroll
        for (int s = 0; s < 2; ++s) {
            #pragma unroll
            for (int nt2 = 0; nt2 < 16; ++nt2)
                #pragma unroll
                for (int r = 0; r < 4; ++r)
                    sO[((s * 16 + nt2) * 4 + r) * 64 + lane] = O[s][nt2][r];
            #pragma unroll
            for (int r = 0; r < 4; ++r)
                sL[(s * 4 + r) * 64 + lane] = lacc[s][r];
        }
    }
    __syncthreads();
    if (kh == 0) {
        float linv[2][4];
        #pragma unroll
        for (int s = 0; s < 2; ++s)
            #pragma unroll
            for (int r = 0; r < 4; ++r) {
                float ls = lacc[s][r] + sL[(s * 4 + r) * 64 + lane];
                #pragma unroll
                for (int off = 1; off < 16; off <<= 1)
                    ls += __shfl_xor(ls, off, 64);
                linv[s][r] = 1.0f / ls;
            }
        #pragma unroll
        for (int s = 0; s < 2; ++s)
            #pragma unroll
            for (int nt2 = 0; nt2 < 16; ++nt2) {
                int d = nt2 * 16 + l16;
                #pragma unroll
                for (int r = 0; r < 4; ++r) {
                    float val = (O[s][nt2][r] + sO[((s * 16 + nt2) * 4 + r) * 64 + lane]) * linv[s][r];
                    attn[bbase + (size_t)(qrow + s * 16 + quad * 4 + r) * CDIM + d] = f2bf(val);
                }
            }
    }
}

// ---------------- output projection + bias + residual, 2-way column-split ---
__global__ __launch_bounds__(128) void oproj_kernel(
        const unsigned short* __restrict__ attn,
        const unsigned short* __restrict__ wo_t,
        const float* __restrict__ bo,
        const float* __restrict__ x,
        float* __restrict__ out) {
    int w = threadIdx.x >> 6, lane = threadIdx.x & 63;
    int quad = lane >> 4, l16 = lane & 15;
    int tok_base = blockIdx.x * 64 + w * 32;
    int nt0 = blockIdx.y * 8;

    bf16x8 afr[2][8];
    #pragma unroll
    for (int s = 0; s < 2; ++s)
        #pragma unroll
        for (int kk = 0; kk < 8; ++kk)
            afr[s][kk] = *(const bf16x8*)(attn + (size_t)(tok_base + s * 16 + l16) * CDIM + kk * 32 + quad * 8);

    #pragma unroll
    for (int ntl = 0; ntl < 8; ++ntl) {
        int nt = nt0 + ntl;
        f32x4 acc0 = {0.f, 0.f, 0.f, 0.f};
        f32x4 acc1 = {0.f, 0.f, 0.f, 0.f};
        #pragma unroll
        for (int kk = 0; kk < 8; ++kk) {
            bf16x8 bfr = *(const bf16x8*)(wo_t + (size_t)(nt * 16 + l16) * CDIM + kk * 32 + quad * 8);
            acc0 = __builtin_amdgcn_mfma_f32_16x16x32_bf16(afr[0][kk], bfr, acc0, 0, 0, 0);
            acc1 = __builtin_amdgcn_mfma_f32_16x16x32_bf16(afr[1][kk], bfr, acc1, 0, 0, 0);
        }
        int d = nt * 16 + l16;
        float bb = bo[d];
        #pragma unroll
        for (int r = 0; r < 4; ++r) {
            size_t idx0 = (size_t)(tok_base + quad * 4 + r) * CDIM + d;
            size_t idx1 = (size_t)(tok_base + 16 + quad * 4 + r) * CDIM + d;
            out[idx0] = x[idx0] + acc0[r] + bb;
            out[idx1] = x[idx1] + acc1[r] + bb;
        }
    }
}

extern "C" void kernel_launch(void* const* d_in, const int* in_sizes, int n_in,
                              void* d_out, int out_size, void* d_ws, size_t ws_size,
                              hipStream_t stream) {
    const float* x     = (const float*)d_in[0];
    const float* gamma = (const float*)d_in[1];
    const float* beta  = (const float*)d_in[2];
    const float* wq    = (const float*)d_in[3];
    const float* bq    = (const float*)d_in[4];
    const float* wk    = (const float*)d_in[5];
    const float* bk    = (const float*)d_in[6];
    const float* wv    = (const float*)d_in[7];
    const float* bv    = (const float*)d_in[8];
    const float* wo    = (const float*)d_in[9];
    const float* bo    = (const float*)d_in[10];
    float* out = (float*)d_out;

    // workspace layout (bytes):
    //   h    @ 0          16,777,216   (LN output; reused for attn)
    //   q    @ 16,777,216 16,777,216
    //   k2   @ 33,554,432 16,777,216   (swizzled tiled K: 512 tiles x 64 x 256)
    //   vt2  @ 50,331,648 16,777,216   (swizzled tiled Vt: 512 tiles x 256 x 64)
    //   wt   @ 67,108,864    524,288   (4 transposed bf16 weight matrices)
    char* ws = (char*)d_ws;
    unsigned short* h_bf = (unsigned short*)(ws);
    unsigned short* q_bf = (unsigned short*)(ws + 16777216);
    unsigned short* k2   = (unsigned short*)(ws + 33554432);
    unsigned short* vt2  = (unsigned short*)(ws + 50331648);
    unsigned short* wt   = (unsigned short*)(ws + 67108864);
    unsigned short* attn = h_bf;   // h dead after qkv

    prep_kernel<<<TOK / 4 + 1024, 256, 0, stream>>>(x, gamma, beta, wq, wk, wv, wo, h_bf, wt);
    qkv_kernel<<<dim3(TOK / 64, 4), 128, 0, stream>>>(h_bf, wt, bq, bk, bv, q_bf, k2, vt2);
    flash_kernel<<<(NTOK / BQ) * NB, 512, 0, stream>>>(q_bf, k2, vt2, attn);
    oproj_kernel<<<dim3(TOK / 64, 2), 128, 0, stream>>>(attn, wt + 3 * (CDIM * CDIM), bo, x, out);
}

// Round 4
// 410.644 us; speedup vs baseline: 1.2225x; 1.2225x over previous
//
#include <hip/hip_runtime.h>
#include <stdint.h>

// Problem constants: B=8, H=W=64, C=256
#define NB    8
#define NTOK  4096          // H*W tokens per batch
#define TOK   32768         // NB*NTOK
#define CDIM  256
#define BQ    128           // queries per block (flash): 16 per wave (8 q-groups)
#define BK    64            // keys per LDS tile (flash); split 32/32 across wave halves
#define NT    (NTOK / BK)   // 64 key tiles

#define KPITCH 264          // Ks row pitch in shorts (pad +8, baked into k2 global)
#define VPITCH 68           // Vs row pitch in shorts (pad +4, baked into vt2 global)
#define KTILE_SH (BK * KPITCH)     // 16896 shorts = 33792 B
#define VTILE_SH (CDIM * VPITCH)   // 17408 shorts = 34816 B
#define KCH   33
#define VCH   34
#define TOTCH (KCH + VCH)   // 67 1-KB DMA chunks per tile

typedef __attribute__((ext_vector_type(8))) short bf16x8;   // 8 bf16 = 4 VGPRs
typedef __attribute__((ext_vector_type(4))) float f32x4;    // MFMA C/D frag

#define SSCALE 0.09016844f   // C^-0.5 * log2(e) = 0.0625 * 1.442695

static __device__ __forceinline__ unsigned short f2bf(float f) {
    union { float f; unsigned u; } v; v.f = f;
    unsigned r = v.u + 0x7fffu + ((v.u >> 16) & 1u);   // RNE
    return (unsigned short)(r >> 16);
}

// async global->LDS DMA: 16 B/lane, LDS dest = uniform base + lane*16
static __device__ __forceinline__ void dma16(const unsigned short* g, unsigned short* l) {
    __builtin_amdgcn_global_load_lds(
        (const __attribute__((address_space(1))) unsigned int*)g,
        (__attribute__((address_space(3))) unsigned int*)l,
        16, 0, 0);
}

// ---------------- prep: LayerNorm (blocks 0..8191) + weight transpose -------
__global__ __launch_bounds__(256) void prep_kernel(
        const float* __restrict__ x,
        const float* __restrict__ gamma,
        const float* __restrict__ beta,
        const float* __restrict__ w0, const float* __restrict__ w1,
        const float* __restrict__ w2, const float* __restrict__ w3,
        unsigned short* __restrict__ h_bf,
        unsigned short* __restrict__ wt) {
    int bx = blockIdx.x;
    if (bx >= TOK / 4) {
        // weight transpose + bf16 cast: Wt[d][c] = W[c][d]
        int id = bx - TOK / 4;            // 0..1023
        int m = id >> 8, dd = id & 255;
        const float* src = (m == 0) ? w0 : (m == 1) ? w1 : (m == 2) ? w2 : w3;
        wt[m * (CDIM * CDIM) + dd * CDIM + threadIdx.x] = f2bf(src[threadIdx.x * CDIM + dd]);
        return;
    }
    int w = threadIdx.x >> 6;
    int lane = threadIdx.x & 63;
    int token = bx * 4 + w;
    const float4 xv = ((const float4*)(x + (size_t)token * CDIM))[lane];
    float s = xv.x + xv.y + xv.z + xv.w;
    #pragma unroll
    for (int off = 1; off < 64; off <<= 1) s += __shfl_xor(s, off, 64);
    float mean = s * (1.0f / 256.0f);
    float d0 = xv.x - mean, d1 = xv.y - mean, d2 = xv.z - mean, d3 = xv.w - mean;
    float ss = d0 * d0 + d1 * d1 + d2 * d2 + d3 * d3;
    #pragma unroll
    for (int off = 1; off < 64; off <<= 1) ss += __shfl_xor(ss, off, 64);
    float rstd = rsqrtf(ss * (1.0f / 256.0f) + 1e-5f);
    float4 g = ((const float4*)gamma)[lane];
    float4 b = ((const float4*)beta)[lane];
    ushort4 o;
    o.x = f2bf(d0 * rstd * g.x + b.x);
    o.y = f2bf(d1 * rstd * g.y + b.y);
    o.z = f2bf(d2 * rstd * g.z + b.z);
    o.w = f2bf(d3 * rstd * g.w + b.w);
    ((ushort4*)(h_bf + (size_t)token * CDIM))[lane] = o;
}

// ---------------- fused Q+K+V projection, 4-way column-split ----------------
// grid (512, 4), 128 thr. Block (bx,gy) = key tile bx, output columns
// nt = gy*4 .. gy*4+3 of ALL THREE projections. (round-0 version, padded tiles)
__global__ __launch_bounds__(128) void qkv_kernel(
        const unsigned short* __restrict__ h_bf,
        const unsigned short* __restrict__ wts,
        const float* __restrict__ bq,
        const float* __restrict__ bk,
        const float* __restrict__ bv,
        unsigned short* __restrict__ q_bf,
        unsigned short* __restrict__ k2,
        unsigned short* __restrict__ vt2) {
    __shared__ unsigned short VT[64][VPITCH];   // 8704 B (quarter tile: d in [gy*64, gy*64+64))
    int tid = threadIdx.x;
    int w = tid >> 6, lane = tid & 63, quad = lane >> 4, l16 = lane & 15;
    int blk = blockIdx.x;
    int gy = blockIdx.y;
    int nt0 = gy * 4;
    int tok_base = blk * 64 + w * 32;

    bf16x8 afr[2][8];
    #pragma unroll
    for (int s = 0; s < 2; ++s)
        #pragma unroll
        for (int kk = 0; kk < 8; ++kk)
            afr[s][kk] = *(const bf16x8*)(h_bf + (size_t)(tok_base + s * 16 + l16) * CDIM + kk * 32 + quad * 8);

    // ---- Q (pre-scaled by SSCALE)
    {
        const unsigned short* wq_t = wts;
        #pragma unroll
        for (int ntl = 0; ntl < 4; ++ntl) {
            int nt = nt0 + ntl;
            f32x4 acc0 = {0.f, 0.f, 0.f, 0.f};
            f32x4 acc1 = {0.f, 0.f, 0.f, 0.f};
            #pragma unroll
            for (int kk = 0; kk < 8; ++kk) {
                bf16x8 bfr = *(const bf16x8*)(wq_t + (size_t)(nt * 16 + l16) * CDIM + kk * 32 + quad * 8);
                acc0 = __builtin_amdgcn_mfma_f32_16x16x32_bf16(afr[0][kk], bfr, acc0, 0, 0, 0);
                acc1 = __builtin_amdgcn_mfma_f32_16x16x32_bf16(afr[1][kk], bfr, acc1, 0, 0, 0);
            }
            int d = nt * 16 + l16;
            float bb = bq[d];
            #pragma unroll
            for (int r = 0; r < 4; ++r) {
                q_bf[(size_t)(tok_base + quad * 4 + r) * CDIM + d]      = f2bf((acc0[r] + bb) * SSCALE);
                q_bf[(size_t)(tok_base + 16 + quad * 4 + r) * CDIM + d] = f2bf((acc1[r] + bb) * SSCALE);
            }
        }
    }
    // ---- K (into padded tile)
    {
        const unsigned short* wk_t = wts + CDIM * CDIM;
        unsigned short* kdst = k2 + (size_t)blk * KTILE_SH;
        int row0 = w * 32 + quad * 4;
        #pragma unroll
        for (int ntl = 0; ntl < 4; ++ntl) {
            int nt = nt0 + ntl;
            f32x4 acc0 = {0.f, 0.f, 0.f, 0.f};
            f32x4 acc1 = {0.f, 0.f, 0.f, 0.f};
            #pragma unroll
            for (int kk = 0; kk < 8; ++kk) {
                bf16x8 bfr = *(const bf16x8*)(wk_t + (size_t)(nt * 16 + l16) * CDIM + kk * 32 + quad * 8);
                acc0 = __builtin_amdgcn_mfma_f32_16x16x32_bf16(afr[0][kk], bfr, acc0, 0, 0, 0);
                acc1 = __builtin_amdgcn_mfma_f32_16x16x32_bf16(afr[1][kk], bfr, acc1, 0, 0, 0);
            }
            int d = nt * 16 + l16;
            float bb = bk[d];
            #pragma unroll
            for (int r = 0; r < 4; ++r) {
                kdst[(size_t)(row0 + r) * KPITCH + d]      = f2bf(acc0[r] + bb);
                kdst[(size_t)(row0 + 16 + r) * KPITCH + d] = f2bf(acc1[r] + bb);
            }
        }
    }
    // ---- V (transpose through quarter-height LDS into padded tile)
    {
        const unsigned short* wv_t = wts + 2 * CDIM * CDIM;
        int col0 = w * 32 + quad * 4;
        #pragma unroll
        for (int ntl = 0; ntl < 4; ++ntl) {
            int nt = nt0 + ntl;
            f32x4 acc0 = {0.f, 0.f, 0.f, 0.f};
            f32x4 acc1 = {0.f, 0.f, 0.f, 0.f};
            #pragma unroll
            for (int kk = 0; kk < 8; ++kk) {
                bf16x8 bfr = *(const bf16x8*)(wv_t + (size_t)(nt * 16 + l16) * CDIM + kk * 32 + quad * 8);
                acc0 = __builtin_amdgcn_mfma_f32_16x16x32_bf16(afr[0][kk], bfr, acc0, 0, 0, 0);
                acc1 = __builtin_amdgcn_mfma_f32_16x16x32_bf16(afr[1][kk], bfr, acc1, 0, 0, 0);
            }
            int d = nt * 16 + l16;
            float bb = bv[d];
            int dl = ntl * 16 + l16;          // local row (d - gy*64)
            #pragma unroll
            for (int r = 0; r < 4; ++r) {
                VT[dl][col0 + r]      = f2bf(acc0[r] + bb);
                VT[dl][col0 + 16 + r] = f2bf(acc1[r] + bb);
            }
        }
    }
    __syncthreads();
    // flat coalesced copy-out: 544 uint4 over 128 threads
    const uint4* src = (const uint4*)(&VT[0][0]);
    uint4* dst = (uint4*)(vt2 + (size_t)blk * VTILE_SH + (size_t)gy * 64 * VPITCH);
    #pragma unroll
    for (int i = 0; i < 4; ++i)
        dst[i * 128 + tid] = src[i * 128 + tid];
    if (tid < 32) dst[512 + tid] = src[512 + tid];
}

// ---------------- Flash attention: 16 waves (4/SIMD), key-split wave pairs ---
// Round-0 structure (layouts, DMA, __syncthreads pipeline, P roundtrip,
// pair-combine epilogue) with ONE change: 1024 thr / 16 waves per block
// instead of 512/8. Wave w = q-group (w&7, 16 rows) x key half (w>>3).
// Grid stays 256 -> 1 block/CU -> 4 waves/SIMD (was 2): dependency stalls in
// the QK->softmax->P-LDS->PV chain now hide behind 3 other waves per SIMD.
// Per-CU MFMA work unchanged; O accumulator halves to 64 regs so 16 waves fit
// the <=128 reg/wave budget.
#define DMA_TILE(KS, VS, ktn)                                                        \
    {                                                                                \
        const unsigned short* gk = k2 + (size_t)(b * NT + (ktn)) * KTILE_SH;         \
        const unsigned short* gv = vt2 + (size_t)(b * NT + (ktn)) * VTILE_SH;        \
        for (int c = w; c < TOTCH; c += 16) {                                        \
            if (c < KCH) dma16(gk + c * 512 + lane * 8, &KS[0][0] + c * 512);        \
            else dma16(gv + (c - KCH) * 512 + lane * 8, &VS[0][0] + (c - KCH) * 512);\
        }                                                                            \
    }

#define COMPUTE_TILE(KS, VS)                                                         \
    {                                                                                \
        f32x4 sfr[2];                                                                \
        _Pragma("unroll")                                                            \
        for (int nt = 0; nt < 2; ++nt) {                                             \
            f32x4 a0 = {0.f, 0.f, 0.f, 0.f};                                         \
            _Pragma("unroll")                                                        \
            for (int kk = 0; kk < 8; ++kk) {                                         \
                bf16x8 kb = *(const bf16x8*)(&KS[kh * 32 + nt * 16 + l16][kk * 32 + quad * 8]); \
                a0 = __builtin_amdgcn_mfma_f32_16x16x32_bf16(qfr[kk], kb, a0, 0, 0, 0);         \
            }                                                                        \
            sfr[nt] = a0;                                                            \
        }                                                                            \
        _Pragma("unroll")                                                            \
        for (int nt = 0; nt < 2; ++nt)                                               \
            _Pragma("unroll")                                                        \
            for (int r = 0; r < 4; ++r) {                                            \
                float p = exp2f(sfr[nt][r]);                                         \
                lacc[r] += p;                                                        \
                Pl[wq * 16 + quad * 4 + r][kh * 32 + nt * 16 + l16] =                \
                    (unsigned short)(__float_as_uint(p) >> 16);                      \
            }                                                                        \
        bf16x8 pfr = *(const bf16x8*)(&Pl[wq * 16 + l16][kh * 32 + quad * 8]);       \
        _Pragma("unroll")                                                            \
        for (int nt2 = 0; nt2 < 16; ++nt2) {                                         \
            bf16x8 vb = *(const bf16x8*)(&VS[nt2 * 16 + l16][kh * 32 + quad * 8]);   \
            O[nt2] = __builtin_amdgcn_mfma_f32_16x16x32_bf16(pfr, vb, O[nt2], 0, 0, 0);         \
        }                                                                            \
    }

__global__ __launch_bounds__(1024, 4) void flash_kernel(
        const unsigned short* __restrict__ q_bf,
        const unsigned short* __restrict__ k2,
        const unsigned short* __restrict__ vt2,
        unsigned short* __restrict__ attn) {
    __shared__ unsigned short Ks0[BK][KPITCH];    // 33792 B
    __shared__ unsigned short Ks1[BK][KPITCH];    // 33792 B
    __shared__ unsigned short Vs0[CDIM][VPITCH];  // 34816 B
    __shared__ unsigned short Vs1[CDIM][VPITCH];  // 34816 B
    __shared__ unsigned short Pl[BQ][VPITCH];     // 17408 B  (total 154.6 KB)

    int tid = threadIdx.x;
    int w = tid >> 6, lane = tid & 63, quad = lane >> 4, l16 = lane & 15;
    int kh = w >> 3;        // key half of each tile
    int wq = w & 7;         // q-row group (16 rows; shared with wave w^8)
    int bid = blockIdx.x;
    int b = bid & 7;        // XCD swizzle: same batch -> same XCD L2
    int qtile = bid >> 3;
    int qrow = qtile * BQ + wq * 16;
    const size_t bbase = (size_t)b * NTOK * CDIM;

    bf16x8 qfr[8];
    #pragma unroll
    for (int kk = 0; kk < 8; ++kk)
        qfr[kk] = *(const bf16x8*)(q_bf + bbase + (size_t)(qrow + l16) * CDIM + kk * 32 + quad * 8);

    f32x4 O[16];
    #pragma unroll
    for (int i = 0; i < 16; ++i) O[i] = (f32x4){0.f, 0.f, 0.f, 0.f};
    float lacc[4] = {0.f, 0.f, 0.f, 0.f};

    DMA_TILE(Ks0, Vs0, 0);
    __syncthreads();

    for (int kt2 = 0; kt2 < NT; kt2 += 2) {
        DMA_TILE(Ks1, Vs1, kt2 + 1);
        COMPUTE_TILE(Ks0, Vs0);
        __syncthreads();
        if (kt2 + 2 < NT) DMA_TILE(Ks0, Vs0, kt2 + 2);
        COMPUTE_TILE(Ks1, Vs1);
        __syncthreads();
    }

    // ---- epilogue: combine wave pairs (key halves) through dead LDS buffers
    // 8 pairs; pair wq exchanges O[16][4] (16 KB) + lacc[4] (1 KB).
    float* sO = ((wq < 2) ? (float*)&Ks0[0][0] : (wq < 4) ? (float*)&Ks1[0][0]
               : (wq < 6) ? (float*)&Vs0[0][0] : (float*)&Vs1[0][0]) + (wq & 1) * 4096;
    float* sL = (float*)&Pl[0][0] + wq * 256;

    if (kh == 1) {
        #pragma unroll
        for (int nt2 = 0; nt2 < 16; ++nt2)
            #pragma unroll
            for (int r = 0; r < 4; ++r)
                sO[(nt2 * 4 + r) * 64 + lane] = O[nt2][r];
        #pragma unroll
        for (int r = 0; r < 4; ++r)
            sL[r * 64 + lane] = lacc[r];
    }
    __syncthreads();
    if (kh == 0) {
        float linv[4];
        #pragma unroll
        for (int r = 0; r < 4; ++r) {
            float ls = lacc[r] + sL[r * 64 + lane];
            #pragma unroll
            for (int off = 1; off < 16; off <<= 1)
                ls += __shfl_xor(ls, off, 64);
            linv[r] = 1.0f / ls;
        }
        #pragma unroll
        for (int nt2 = 0; nt2 < 16; ++nt2) {
            int d = nt2 * 16 + l16;
            #pragma unroll
            for (int r = 0; r < 4; ++r) {
                float val = (O[nt2][r] + sO[(nt2 * 4 + r) * 64 + lane]) * linv[r];
                attn[bbase + (size_t)(qrow + quad * 4 + r) * CDIM + d] = f2bf(val);
            }
        }
    }
}

// ---------------- output projection + bias + residual, 2-way column-split ---
__global__ __launch_bounds__(128) void oproj_kernel(
        const unsigned short* __restrict__ attn,
        const unsigned short* __restrict__ wo_t,
        const float* __restrict__ bo,
        const float* __restrict__ x,
        float* __restrict__ out) {
    int w = threadIdx.x >> 6, lane = threadIdx.x & 63;
    int quad = lane >> 4, l16 = lane & 15;
    int tok_base = blockIdx.x * 64 + w * 32;
    int nt0 = blockIdx.y * 8;

    bf16x8 afr[2][8];
    #pragma unroll
    for (int s = 0; s < 2; ++s)
        #pragma unroll
        for (int kk = 0; kk < 8; ++kk)
            afr[s][kk] = *(const bf16x8*)(attn + (size_t)(tok_base + s * 16 + l16) * CDIM + kk * 32 + quad * 8);

    #pragma unroll
    for (int ntl = 0; ntl < 8; ++ntl) {
        int nt = nt0 + ntl;
        f32x4 acc0 = {0.f, 0.f, 0.f, 0.f};
        f32x4 acc1 = {0.f, 0.f, 0.f, 0.f};
        #pragma unroll
        for (int kk = 0; kk < 8; ++kk) {
            bf16x8 bfr = *(const bf16x8*)(wo_t + (size_t)(nt * 16 + l16) * CDIM + kk * 32 + quad * 8);
            acc0 = __builtin_amdgcn_mfma_f32_16x16x32_bf16(afr[0][kk], bfr, acc0, 0, 0, 0);
            acc1 = __builtin_amdgcn_mfma_f32_16x16x32_bf16(afr[1][kk], bfr, acc1, 0, 0, 0);
        }
        int d = nt * 16 + l16;
        float bb = bo[d];
        #pragma unroll
        for (int r = 0; r < 4; ++r) {
            size_t idx0 = (size_t)(tok_base + quad * 4 + r) * CDIM + d;
            size_t idx1 = (size_t)(tok_base + 16 + quad * 4 + r) * CDIM + d;
            out[idx0] = x[idx0] + acc0[r] + bb;
            out[idx1] = x[idx1] + acc1[r] + bb;
        }
    }
}

extern "C" void kernel_launch(void* const* d_in, const int* in_sizes, int n_in,
                              void* d_out, int out_size, void* d_ws, size_t ws_size,
                              hipStream_t stream) {
    const float* x     = (const float*)d_in[0];
    const float* gamma = (const float*)d_in[1];
    const float* beta  = (const float*)d_in[2];
    const float* wq    = (const float*)d_in[3];
    const float* bq    = (const float*)d_in[4];
    const float* wk    = (const float*)d_in[5];
    const float* bk    = (const float*)d_in[6];
    const float* wv    = (const float*)d_in[7];
    const float* bv    = (const float*)d_in[8];
    const float* wo    = (const float*)d_in[9];
    const float* bo    = (const float*)d_in[10];
    float* out = (float*)d_out;

    // workspace layout (bytes):
    //   h    @ 0          16,777,216   (LN output; reused for attn)
    //   q    @ 16,777,216 16,777,216
    //   k2   @ 33,554,432 17,301,504   (padded tiled K: 512 tiles x 64 x 264)
    //   vt2  @ 50,855,936 17,825,792   (padded tiled Vt: 512 tiles x 256 x 68)
    //   wt   @ 68,681,728    524,288   (4 transposed bf16 weight matrices)
    char* ws = (char*)d_ws;
    unsigned short* h_bf = (unsigned short*)(ws);
    unsigned short* q_bf = (unsigned short*)(ws + 16777216);
    unsigned short* k2   = (unsigned short*)(ws + 33554432);
    unsigned short* vt2  = (unsigned short*)(ws + 50855936);
    unsigned short* wt   = (unsigned short*)(ws + 68681728);
    unsigned short* attn = h_bf;   // h dead after qkv

    prep_kernel<<<TOK / 4 + 1024, 256, 0, stream>>>(x, gamma, beta, wq, wk, wv, wo, h_bf, wt);
    qkv_kernel<<<dim3(TOK / 64, 4), 128, 0, stream>>>(h_bf, wt, bq, bk, bv, q_bf, k2, vt2);
    flash_kernel<<<(NTOK / BQ) * NB, 1024, 0, stream>>>(q_bf, k2, vt2, attn);
    oproj_kernel<<<dim3(TOK / 64, 2), 128, 0, stream>>>(attn, wt + 3 * (CDIM * CDIM), bo, x, out);
}

// Round 5
// 363.385 us; speedup vs baseline: 1.3815x; 1.1301x over previous
//
#include <hip/hip_runtime.h>
#include <stdint.h>

// Problem constants: B=8, H=W=64, C=256
#define NB    8
#define NTOK  4096          // H*W tokens per batch
#define TOK   32768         // NB*NTOK
#define CDIM  256
#define BQ    128           // queries per block (flash): 32 per wave-pair
#define BK    64            // keys per LDS tile (flash); split 32/32 across wave halves
#define NT    (NTOK / BK)   // 64 key tiles

#define KPITCH 264          // Ks row pitch in shorts (pad +8, baked into k2 global)
#define VPITCH 68           // Vs row pitch in shorts (pad +4, baked into vt2 global)
#define KTILE_SH (BK * KPITCH)     // 16896 shorts = 33792 B
#define VTILE_SH (CDIM * VPITCH)   // 17408 shorts = 34816 B
#define KCH   33
#define VCH   34
#define TOTCH (KCH + VCH)   // 67 1-KB DMA chunks per tile

typedef __attribute__((ext_vector_type(8))) short bf16x8;   // 8 bf16 = 4 VGPRs
typedef __attribute__((ext_vector_type(4))) float f32x4;    // MFMA C/D frag

#define SSCALE 0.09016844f   // C^-0.5 * log2(e) = 0.0625 * 1.442695

static __device__ __forceinline__ unsigned short f2bf(float f) {
    union { float f; unsigned u; } v; v.f = f;
    unsigned r = v.u + 0x7fffu + ((v.u >> 16) & 1u);   // RNE
    return (unsigned short)(r >> 16);
}

// async global->LDS DMA: 16 B/lane, LDS dest = uniform base + lane*16
static __device__ __forceinline__ void dma16(const unsigned short* g, unsigned short* l) {
    __builtin_amdgcn_global_load_lds(
        (const __attribute__((address_space(1))) unsigned int*)g,
        (__attribute__((address_space(3))) unsigned int*)l,
        16, 0, 0);
}

// ---------------- prep: LayerNorm (blocks 0..8191) + weight transpose -------
__global__ __launch_bounds__(256) void prep_kernel(
        const float* __restrict__ x,
        const float* __restrict__ gamma,
        const float* __restrict__ beta,
        const float* __restrict__ w0, const float* __restrict__ w1,
        const float* __restrict__ w2, const float* __restrict__ w3,
        unsigned short* __restrict__ h_bf,
        unsigned short* __restrict__ wt) {
    int bx = blockIdx.x;
    if (bx >= TOK / 4) {
        // weight transpose + bf16 cast: Wt[d][c] = W[c][d]
        int id = bx - TOK / 4;            // 0..1023
        int m = id >> 8, dd = id & 255;
        const float* src = (m == 0) ? w0 : (m == 1) ? w1 : (m == 2) ? w2 : w3;
        wt[m * (CDIM * CDIM) + dd * CDIM + threadIdx.x] = f2bf(src[threadIdx.x * CDIM + dd]);
        return;
    }
    int w = threadIdx.x >> 6;
    int lane = threadIdx.x & 63;
    int token = bx * 4 + w;
    const float4 xv = ((const float4*)(x + (size_t)token * CDIM))[lane];
    float s = xv.x + xv.y + xv.z + xv.w;
    #pragma unroll
    for (int off = 1; off < 64; off <<= 1) s += __shfl_xor(s, off, 64);
    float mean = s * (1.0f / 256.0f);
    float d0 = xv.x - mean, d1 = xv.y - mean, d2 = xv.z - mean, d3 = xv.w - mean;
    float ss = d0 * d0 + d1 * d1 + d2 * d2 + d3 * d3;
    #pragma unroll
    for (int off = 1; off < 64; off <<= 1) ss += __shfl_xor(ss, off, 64);
    float rstd = rsqrtf(ss * (1.0f / 256.0f) + 1e-5f);
    float4 g = ((const float4*)gamma)[lane];
    float4 b = ((const float4*)beta)[lane];
    ushort4 o;
    o.x = f2bf(d0 * rstd * g.x + b.x);
    o.y = f2bf(d1 * rstd * g.y + b.y);
    o.z = f2bf(d2 * rstd * g.z + b.z);
    o.w = f2bf(d3 * rstd * g.w + b.w);
    ((ushort4*)(h_bf + (size_t)token * CDIM))[lane] = o;
}

// ---------------- fused Q+K+V projection, 4-way column-split ----------------
// grid (512, 4), 128 thr. Block (bx,gy) = key tile bx, output columns
// nt = gy*4 .. gy*4+3 of ALL THREE projections. V key-columns are written
// PERMUTED within each 32-key half (slot = quad*8 + nt*4 + r) so the flash
// kernel's swapped-QK^T P registers feed PV's A-fragment with NO shuffle.
__global__ __launch_bounds__(128) void qkv_kernel(
        const unsigned short* __restrict__ h_bf,
        const unsigned short* __restrict__ wts,
        const float* __restrict__ bq,
        const float* __restrict__ bk,
        const float* __restrict__ bv,
        unsigned short* __restrict__ q_bf,
        unsigned short* __restrict__ k2,
        unsigned short* __restrict__ vt2) {
    __shared__ unsigned short VT[64][VPITCH];   // 8704 B (quarter tile: d in [gy*64, gy*64+64))
    int tid = threadIdx.x;
    int w = tid >> 6, lane = tid & 63, quad = lane >> 4, l16 = lane & 15;
    int blk = blockIdx.x;
    int gy = blockIdx.y;
    int nt0 = gy * 4;
    int tok_base = blk * 64 + w * 32;

    bf16x8 afr[2][8];
    #pragma unroll
    for (int s = 0; s < 2; ++s)
        #pragma unroll
        for (int kk = 0; kk < 8; ++kk)
            afr[s][kk] = *(const bf16x8*)(h_bf + (size_t)(tok_base + s * 16 + l16) * CDIM + kk * 32 + quad * 8);

    // ---- Q (pre-scaled by SSCALE)
    {
        const unsigned short* wq_t = wts;
        #pragma unroll
        for (int ntl = 0; ntl < 4; ++ntl) {
            int nt = nt0 + ntl;
            f32x4 acc0 = {0.f, 0.f, 0.f, 0.f};
            f32x4 acc1 = {0.f, 0.f, 0.f, 0.f};
            #pragma unroll
            for (int kk = 0; kk < 8; ++kk) {
                bf16x8 bfr = *(const bf16x8*)(wq_t + (size_t)(nt * 16 + l16) * CDIM + kk * 32 + quad * 8);
                acc0 = __builtin_amdgcn_mfma_f32_16x16x32_bf16(afr[0][kk], bfr, acc0, 0, 0, 0);
                acc1 = __builtin_amdgcn_mfma_f32_16x16x32_bf16(afr[1][kk], bfr, acc1, 0, 0, 0);
            }
            int d = nt * 16 + l16;
            float bb = bq[d];
            #pragma unroll
            for (int r = 0; r < 4; ++r) {
                q_bf[(size_t)(tok_base + quad * 4 + r) * CDIM + d]      = f2bf((acc0[r] + bb) * SSCALE);
                q_bf[(size_t)(tok_base + 16 + quad * 4 + r) * CDIM + d] = f2bf((acc1[r] + bb) * SSCALE);
            }
        }
    }
    // ---- K (into padded tile)
    {
        const unsigned short* wk_t = wts + CDIM * CDIM;
        unsigned short* kdst = k2 + (size_t)blk * KTILE_SH;
        int row0 = w * 32 + quad * 4;
        #pragma unroll
        for (int ntl = 0; ntl < 4; ++ntl) {
            int nt = nt0 + ntl;
            f32x4 acc0 = {0.f, 0.f, 0.f, 0.f};
            f32x4 acc1 = {0.f, 0.f, 0.f, 0.f};
            #pragma unroll
            for (int kk = 0; kk < 8; ++kk) {
                bf16x8 bfr = *(const bf16x8*)(wk_t + (size_t)(nt * 16 + l16) * CDIM + kk * 32 + quad * 8);
                acc0 = __builtin_amdgcn_mfma_f32_16x16x32_bf16(afr[0][kk], bfr, acc0, 0, 0, 0);
                acc1 = __builtin_amdgcn_mfma_f32_16x16x32_bf16(afr[1][kk], bfr, acc1, 0, 0, 0);
            }
            int d = nt * 16 + l16;
            float bb = bk[d];
            #pragma unroll
            for (int r = 0; r < 4; ++r) {
                kdst[(size_t)(row0 + r) * KPITCH + d]      = f2bf(acc0[r] + bb);
                kdst[(size_t)(row0 + 16 + r) * KPITCH + d] = f2bf(acc1[r] + bb);
            }
        }
    }
    // ---- V (transpose through quarter-height LDS into padded tile)
    // Key columns permuted within each 32-half: local key k32 = nt*16+quad*4+r
    // is stored at slot quad*8 + nt*4 + r (matches flash P-register order).
    {
        const unsigned short* wv_t = wts + 2 * CDIM * CDIM;
        #pragma unroll
        for (int ntl = 0; ntl < 4; ++ntl) {
            int nt = nt0 + ntl;
            f32x4 acc0 = {0.f, 0.f, 0.f, 0.f};
            f32x4 acc1 = {0.f, 0.f, 0.f, 0.f};
            #pragma unroll
            for (int kk = 0; kk < 8; ++kk) {
                bf16x8 bfr = *(const bf16x8*)(wv_t + (size_t)(nt * 16 + l16) * CDIM + kk * 32 + quad * 8);
                acc0 = __builtin_amdgcn_mfma_f32_16x16x32_bf16(afr[0][kk], bfr, acc0, 0, 0, 0);
                acc1 = __builtin_amdgcn_mfma_f32_16x16x32_bf16(afr[1][kk], bfr, acc1, 0, 0, 0);
            }
            int d = nt * 16 + l16;
            float bb = bv[d];
            int dl = ntl * 16 + l16;          // local row (d - gy*64)
            #pragma unroll
            for (int r = 0; r < 4; ++r) {
                VT[dl][w * 32 + quad * 8 + r]     = f2bf(acc0[r] + bb);  // k32 = quad*4+r     (nt=0)
                VT[dl][w * 32 + quad * 8 + 4 + r] = f2bf(acc1[r] + bb);  // k32 = 16+quad*4+r  (nt=1)
            }
        }
    }
    __syncthreads();
    // flat coalesced copy-out: 544 uint4 over 128 threads
    const uint4* src = (const uint4*)(&VT[0][0]);
    uint4* dst = (uint4*)(vt2 + (size_t)blk * VTILE_SH + (size_t)gy * 64 * VPITCH);
    #pragma unroll
    for (int i = 0; i < 4; ++i)
        dst[i * 128 + tid] = src[i * 128 + tid];
    if (tid < 32) dst[512 + tid] = src[512 + tid];
}

// ---------------- Flash attention: key-split wave pairs, DMA double-buffer ---
// Round-0 geometry (8 waves/512 thr, BQ=128, wave w: q-rows (w&3)*32, key
// half w>>2, __syncthreads pipeline) with the P LDS roundtrip ELIMINATED:
//  - QK^T computed swapped: S^T = mfma(K-frag, Q-frag) — same LDS reads, same
//    registers, but each lane now holds a lane-local softmax row
//    (q = s*16+l16, keys = nt*16+quad*4+r).
//  - V tile is staged with keys permuted (qkv) so the packed P registers ARE
//    the PV A-fragment: zero cross-lane ops, no Pl buffer, no ds_write/read,
//    no write->read lgkm dependency. LDS drops 154.6 -> 136 KB.
#define DMA_TILE(KS, VS, ktn)                                                        \
    {                                                                                \
        const unsigned short* gk = k2 + (size_t)(b * NT + (ktn)) * KTILE_SH;         \
        const unsigned short* gv = vt2 + (size_t)(b * NT + (ktn)) * VTILE_SH;        \
        for (int c = w; c < TOTCH; c += 8) {                                         \
            if (c < KCH) dma16(gk + c * 512 + lane * 8, &KS[0][0] + c * 512);        \
            else dma16(gv + (c - KCH) * 512 + lane * 8, &VS[0][0] + (c - KCH) * 512);\
        }                                                                            \
    }

#define COMPUTE_TILE(KS, VS)                                                         \
    {                                                                                \
        f32x4 sfr[2][2];                                                             \
        _Pragma("unroll")                                                            \
        for (int nt = 0; nt < 2; ++nt) {                                             \
            f32x4 a0 = {0.f, 0.f, 0.f, 0.f};                                         \
            f32x4 a1 = {0.f, 0.f, 0.f, 0.f};                                         \
            _Pragma("unroll")                                                        \
            for (int kk = 0; kk < 8; ++kk) {                                         \
                bf16x8 kb = *(const bf16x8*)(&KS[kh * 32 + nt * 16 + l16][kk * 32 + quad * 8]); \
                a0 = __builtin_amdgcn_mfma_f32_16x16x32_bf16(kb, qfr[0][kk], a0, 0, 0, 0);      \
                a1 = __builtin_amdgcn_mfma_f32_16x16x32_bf16(kb, qfr[1][kk], a1, 0, 0, 0);      \
            }                                                                        \
            sfr[0][nt] = a0; sfr[1][nt] = a1;                                        \
        }                                                                            \
        int4 pwv[2];                                                                 \
        _Pragma("unroll")                                                            \
        for (int s = 0; s < 2; ++s) {                                                \
            unsigned pw[4];                                                          \
            _Pragma("unroll")                                                        \
            for (int nt = 0; nt < 2; ++nt)                                           \
                _Pragma("unroll")                                                    \
                for (int h = 0; h < 2; ++h) {                                        \
                    float plo = exp2f(sfr[s][nt][2 * h]);                            \
                    float phi = exp2f(sfr[s][nt][2 * h + 1]);                        \
                    lacc[s] += plo + phi;                                            \
                    pw[nt * 2 + h] = (__float_as_uint(plo) >> 16)                    \
                                   | (__float_as_uint(phi) & 0xffff0000u);           \
                }                                                                    \
            pwv[s] = make_int4(pw[0], pw[1], pw[2], pw[3]);                          \
        }                                                                            \
        bf16x8 pfr0 = *(bf16x8*)&pwv[0];                                             \
        bf16x8 pfr1 = *(bf16x8*)&pwv[1];                                             \
        _Pragma("unroll")                                                            \
        for (int nt2 = 0; nt2 < 16; ++nt2) {                                         \
            bf16x8 vb = *(const bf16x8*)(&VS[nt2 * 16 + l16][kh * 32 + quad * 8]);   \
            O[0][nt2] = __builtin_amdgcn_mfma_f32_16x16x32_bf16(pfr0, vb, O[0][nt2], 0, 0, 0);  \
            O[1][nt2] = __builtin_amdgcn_mfma_f32_16x16x32_bf16(pfr1, vb, O[1][nt2], 0, 0, 0);  \
        }                                                                            \
    }

__global__ __launch_bounds__(512, 2) void flash_kernel(
        const unsigned short* __restrict__ q_bf,
        const unsigned short* __restrict__ k2,
        const unsigned short* __restrict__ vt2,
        unsigned short* __restrict__ attn) {
    __shared__ unsigned short Ks0[BK][KPITCH];    // 33792 B
    __shared__ unsigned short Ks1[BK][KPITCH];    // 33792 B
    __shared__ unsigned short Vs0[CDIM][VPITCH];  // 34816 B
    __shared__ unsigned short Vs1[CDIM][VPITCH];  // 34816 B
    __shared__ float sLbuf[512];                  // 2048 B  (total 139.3 KB)

    int tid = threadIdx.x;
    int w = tid >> 6, lane = tid & 63, quad = lane >> 4, l16 = lane & 15;
    int kh = w >> 2;        // key half of each tile
    int wq = w & 3;         // q-row group (shared with wave w^4)
    int bid = blockIdx.x;
    int b = bid & 7;        // XCD swizzle: same batch -> same XCD L2
    int qtile = bid >> 3;
    int qrow = qtile * BQ + wq * 32;
    const size_t bbase = (size_t)b * NTOK * CDIM;

    bf16x8 qfr[2][8];
    #pragma unroll
    for (int s = 0; s < 2; ++s)
        #pragma unroll
        for (int kk = 0; kk < 8; ++kk)
            qfr[s][kk] = *(const bf16x8*)(q_bf + bbase + (size_t)(qrow + s * 16 + l16) * CDIM + kk * 32 + quad * 8);

    f32x4 O[2][16];
    #pragma unroll
    for (int s = 0; s < 2; ++s)
        #pragma unroll
        for (int i = 0; i < 16; ++i) O[s][i] = (f32x4){0.f, 0.f, 0.f, 0.f};
    float lacc[2] = {0.f, 0.f};   // per-lane: q = s*16+l16, this quad's 8 keys/tile

    DMA_TILE(Ks0, Vs0, 0);
    __syncthreads();

    for (int kt2 = 0; kt2 < NT; kt2 += 2) {
        DMA_TILE(Ks1, Vs1, kt2 + 1);
        COMPUTE_TILE(Ks0, Vs0);
        __syncthreads();
        if (kt2 + 2 < NT) DMA_TILE(Ks0, Vs0, kt2 + 2);
        COMPUTE_TILE(Ks1, Vs1);
        __syncthreads();
    }

    // ---- epilogue: combine wave pairs (key halves) through dead LDS buffers
    float* sO = (wq == 0) ? (float*)&Ks0[0][0] : (wq == 1) ? (float*)&Ks1[0][0]
              : (wq == 2) ? (float*)&Vs0[0][0] : (float*)&Vs1[0][0];
    float* sL = sLbuf + wq * 128;    // 2 x 64 floats per pair

    if (kh == 1) {
        #pragma unroll
        for (int s = 0; s < 2; ++s) {
            #pragma unroll
            for (int nt2 = 0; nt2 < 16; ++nt2)
                #pragma unroll
                for (int r = 0; r < 4; ++r)
                    sO[((s * 16 + nt2) * 4 + r) * 64 + lane] = O[s][nt2][r];
            sL[s * 64 + lane] = lacc[s];
        }
    }
    __syncthreads();
    if (kh == 0) {
        float lr[2][4];
        #pragma unroll
        for (int s = 0; s < 2; ++s) {
            float ls = lacc[s] + sL[s * 64 + lane];   // + pair's partial (same lane mapping)
            ls += __shfl_xor(ls, 16, 64);             // sum the 4 quad partials
            ls += __shfl_xor(ls, 32, 64);
            float li = 1.0f / ls;                     // full denom for q = s*16+l16
            #pragma unroll
            for (int r = 0; r < 4; ++r)
                lr[s][r] = __shfl(li, quad * 4 + r, 64);   // denom for O row quad*4+r
        }
        #pragma unroll
        for (int s = 0; s < 2; ++s)
            #pragma unroll
            for (int nt2 = 0; nt2 < 16; ++nt2) {
                int d = nt2 * 16 + l16;
                #pragma unroll
                for (int r = 0; r < 4; ++r) {
                    float val = (O[s][nt2][r] + sO[((s * 16 + nt2) * 4 + r) * 64 + lane]) * lr[s][r];
                    attn[bbase + (size_t)(qrow + s * 16 + quad * 4 + r) * CDIM + d] = f2bf(val);
                }
            }
    }
}

// ---------------- output projection + bias + residual, 2-way column-split ---
__global__ __launch_bounds__(128) void oproj_kernel(
        const unsigned short* __restrict__ attn,
        const unsigned short* __restrict__ wo_t,
        const float* __restrict__ bo,
        const float* __restrict__ x,
        float* __restrict__ out) {
    int w = threadIdx.x >> 6, lane = threadIdx.x & 63;
    int quad = lane >> 4, l16 = lane & 15;
    int tok_base = blockIdx.x * 64 + w * 32;
    int nt0 = blockIdx.y * 8;

    bf16x8 afr[2][8];
    #pragma unroll
    for (int s = 0; s < 2; ++s)
        #pragma unroll
        for (int kk = 0; kk < 8; ++kk)
            afr[s][kk] = *(const bf16x8*)(attn + (size_t)(tok_base + s * 16 + l16) * CDIM + kk * 32 + quad * 8);

    #pragma unroll
    for (int ntl = 0; ntl < 8; ++ntl) {
        int nt = nt0 + ntl;
        f32x4 acc0 = {0.f, 0.f, 0.f, 0.f};
        f32x4 acc1 = {0.f, 0.f, 0.f, 0.f};
        #pragma unroll
        for (int kk = 0; kk < 8; ++kk) {
            bf16x8 bfr = *(const bf16x8*)(wo_t + (size_t)(nt * 16 + l16) * CDIM + kk * 32 + quad * 8);
            acc0 = __builtin_amdgcn_mfma_f32_16x16x32_bf16(afr[0][kk], bfr, acc0, 0, 0, 0);
            acc1 = __builtin_amdgcn_mfma_f32_16x16x32_bf16(afr[1][kk], bfr, acc1, 0, 0, 0);
        }
        int d = nt * 16 + l16;
        float bb = bo[d];
        #pragma unroll
        for (int r = 0; r < 4; ++r) {
            size_t idx0 = (size_t)(tok_base + quad * 4 + r) * CDIM + d;
            size_t idx1 = (size_t)(tok_base + 16 + quad * 4 + r) * CDIM + d;
            out[idx0] = x[idx0] + acc0[r] + bb;
            out[idx1] = x[idx1] + acc1[r] + bb;
        }
    }
}

extern "C" void kernel_launch(void* const* d_in, const int* in_sizes, int n_in,
                              void* d_out, int out_size, void* d_ws, size_t ws_size,
                              hipStream_t stream) {
    const float* x     = (const float*)d_in[0];
    const float* gamma = (const float*)d_in[1];
    const float* beta  = (const float*)d_in[2];
    const float* wq    = (const float*)d_in[3];
    const float* bq    = (const float*)d_in[4];
    const float* wk    = (const float*)d_in[5];
    const float* bk    = (const float*)d_in[6];
    const float* wv    = (const float*)d_in[7];
    const float* bv    = (const float*)d_in[8];
    const float* wo    = (const float*)d_in[9];
    const float* bo    = (const float*)d_in[10];
    float* out = (float*)d_out;

    // workspace layout (bytes):
    //   h    @ 0          16,777,216   (LN output; reused for attn)
    //   q    @ 16,777,216 16,777,216
    //   k2   @ 33,554,432 17,301,504   (padded tiled K: 512 tiles x 64 x 264)
    //   vt2  @ 50,855,936 17,825,792   (padded tiled Vt: 512 tiles x 256 x 68, keys permuted)
    //   wt   @ 68,681,728    524,288   (4 transposed bf16 weight matrices)
    char* ws = (char*)d_ws;
    unsigned short* h_bf = (unsigned short*)(ws);
    unsigned short* q_bf = (unsigned short*)(ws + 16777216);
    unsigned short* k2   = (unsigned short*)(ws + 33554432);
    unsigned short* vt2  = (unsigned short*)(ws + 50855936);
    unsigned short* wt   = (unsigned short*)(ws + 68681728);
    unsigned short* attn = h_bf;   // h dead after qkv

    prep_kernel<<<TOK / 4 + 1024, 256, 0, stream>>>(x, gamma, beta, wq, wk, wv, wo, h_bf, wt);
    qkv_kernel<<<dim3(TOK / 64, 4), 128, 0, stream>>>(h_bf, wt, bq, bk, bv, q_bf, k2, vt2);
    flash_kernel<<<(NTOK / BQ) * NB, 512, 0, stream>>>(q_bf, k2, vt2, attn);
    oproj_kernel<<<dim3(TOK / 64, 2), 128, 0, stream>>>(attn, wt + 3 * (CDIM * CDIM), bo, x, out);
}